// Round 1
// baseline (732.214 us; speedup 1.0000x reference)
//
#include <hip/hip_runtime.h>

#define N_NODES 50000
#define N_EDGES 800000
#define D 128
#define NPB 32   // nodes per block in the GEMM kernel

// ---------------- CSR build ----------------

__global__ __launch_bounds__(256) void k_count(const int* __restrict__ ei,
                                               int* __restrict__ deg) {
    int e = blockIdx.x * 256 + threadIdx.x;
    if (e < N_EDGES) atomicAdd(&deg[ei[N_EDGES + e]], 1);   // dst = ei[1][e]
}

__global__ __launch_bounds__(1024) void k_scan(const int* __restrict__ deg,
                                               int* __restrict__ rowp) {
    const int CH = (N_NODES + 1023) / 1024;   // 49 elements per thread
    __shared__ int s[1024];
    int t = threadIdx.x;
    int lo = t * CH;
    int hi = lo + CH; if (hi > N_NODES) hi = N_NODES;
    int sum = 0;
    for (int i = lo; i < hi; ++i) sum += deg[i];
    s[t] = sum;
    __syncthreads();
    for (int off = 1; off < 1024; off <<= 1) {
        int u = (t >= off) ? s[t - off] : 0;
        __syncthreads();
        s[t] += u;
        __syncthreads();
    }
    int run = (t > 0) ? s[t - 1] : 0;   // exclusive prefix of this chunk
    for (int i = lo; i < hi; ++i) { rowp[i] = run; run += deg[i]; }
    if (t == 1023) rowp[N_NODES] = s[1023];
}

__global__ __launch_bounds__(256) void k_fill(const int* __restrict__ ei,
                                              const int* __restrict__ rowp,
                                              int* __restrict__ fil,
                                              int* __restrict__ colx) {
    int e = blockIdx.x * 256 + threadIdx.x;
    if (e < N_EDGES) {
        int dst = ei[N_EDGES + e];
        int p = rowp[dst] + atomicAdd(&fil[dst], 1);
        colx[p] = ei[e];                 // src = ei[0][e]
    }
}

// ---------------- mean aggregation: one wave per node ----------------

__global__ __launch_bounds__(256) void k_aggregate(const float* __restrict__ X,
                                                   const int* __restrict__ rowp,
                                                   const int* __restrict__ colx,
                                                   const int* __restrict__ deg,
                                                   float* __restrict__ M) {
    int w = (blockIdx.x * 256 + threadIdx.x) >> 6;   // wave id = node
    int lane = threadIdx.x & 63;
    if (w >= N_NODES) return;
    int start = rowp[w];
    int d = deg[w];
    float ax = 0.f, ay = 0.f;
    for (int j = 0; j < d; ++j) {
        int s = colx[start + j];
        float2 v = ((const float2*)X)[s * 64 + lane];  // 512B coalesced row read
        ax += v.x; ay += v.y;
    }
    float inv = 1.0f / fmaxf((float)d, 1.0f);
    ((float2*)M)[w * 64 + lane] = make_float2(ax * inv, ay * inv);
}

// ---------------- fused GEMM + bias + L2-normalize + activation/residual ----------------
// out[i,t] = normalize_i( b[t] + sum_k M[i,k]*Wl[t,k] + X[i,k]*Wr[t,k] )
// mode 0: leaky_relu -> out (=h1).  mode 1: + h1 -> out.

__global__ __launch_bounds__(128) void k_gemm(const float* __restrict__ M,
                                              const float* __restrict__ X,
                                              const float* __restrict__ Wl,
                                              const float* __restrict__ bl,
                                              const float* __restrict__ Wr,
                                              const float* __restrict__ h1,
                                              float* __restrict__ out,
                                              int mode) {
    __shared__ float AM[NPB][D];
    __shared__ float AX[NPB][D];
    __shared__ float SS[NPB][D + 1];   // pad 129: conflict-free column reduce
    __shared__ float rnrm[NPB];
    int t = threadIdx.x;               // output feature 0..127
    int n0 = blockIdx.x * NPB;

    // stage node tiles (float4, coalesced)
    for (int idx = t; idx < NPB * (D / 4); idx += 128) {
        int row = idx >> 5;            // 32 float4 per row
        int c4 = idx & 31;
        int node = n0 + row;
        float4 vm = make_float4(0, 0, 0, 0), vx = vm;
        if (node < N_NODES) {
            vm = ((const float4*)M)[node * 32 + c4];
            vx = ((const float4*)X)[node * 32 + c4];
        }
        ((float4*)AM[row])[c4] = vm;
        ((float4*)AX[row])[c4] = vx;
    }
    __syncthreads();

    float acc[NPB];
    float bias = bl[t];
    #pragma unroll
    for (int i = 0; i < NPB; ++i) acc[i] = bias;

    const float4* wl4 = (const float4*)(Wl + t * D);   // thread t streams W row t
    const float4* wr4 = (const float4*)(Wr + t * D);
    for (int k4 = 0; k4 < D / 4; ++k4) {
        float4 a = wl4[k4];
        float4 b = wr4[k4];
        #pragma unroll
        for (int i = 0; i < NPB; ++i) {
            float4 m  = ((const float4*)AM[i])[k4];    // LDS broadcast reads
            float4 xx = ((const float4*)AX[i])[k4];
            acc[i] += a.x * m.x + a.y * m.y + a.z * m.z + a.w * m.w;
            acc[i] += b.x * xx.x + b.y * xx.y + b.z * xx.z + b.w * xx.w;
        }
    }

    // per-node L2 norm: acc is distributed across the 128 threads
    #pragma unroll
    for (int i = 0; i < NPB; ++i) SS[i][t] = acc[i];
    __syncthreads();
    if (t < NPB) {
        float s = 0.f;
        for (int k = 0; k < D; ++k) { float v = SS[t][k]; s += v * v; }
        rnrm[t] = 1.0f / fmaxf(sqrtf(s), 1e-12f);
    }
    __syncthreads();

    #pragma unroll
    for (int i = 0; i < NPB; ++i) {
        int node = n0 + i;
        if (node < N_NODES) {
            float v = acc[i] * rnrm[i];
            if (mode == 0) v = (v > 0.f) ? v : 0.01f * v;   // leaky_relu
            else           v += h1[node * D + t];           // h1 + h2
            out[node * D + t] = v;
        }
    }
}

// ---------------- launch ----------------

extern "C" void kernel_launch(void* const* d_in, const int* in_sizes, int n_in,
                              void* d_out, int out_size, void* d_ws, size_t ws_size,
                              hipStream_t stream) {
    const float* x   = (const float*)d_in[0];
    const int*   ei  = (const int*)d_in[1];   // int64 in ref, but JAX x64-off => int32
    const float* W1l = (const float*)d_in[2];
    const float* b1l = (const float*)d_in[3];
    const float* W1r = (const float*)d_in[4];
    const float* W2l = (const float*)d_in[5];
    const float* b2l = (const float*)d_in[6];
    const float* W2r = (const float*)d_in[7];
    float* out = (float*)d_out;
    char*  ws  = (char*)d_ws;

    // workspace layout (bytes): ~28.4 MB total
    int*   deg  = (int*)(ws + 0);         // 200000 B
    int*   fil  = (int*)(ws + 204800);    // 200000 B
    int*   rowp = (int*)(ws + 409600);    // 200004 B
    int*   colx = (int*)(ws + 614400);    // 3.2 MB
    float* M    = (float*)(ws + 4194304); // 25.6 MB (mean buffer, reused per layer)

    hipMemsetAsync(ws, 0, 409600, stream);             // zero deg + fil

    k_count<<<(N_EDGES + 255) / 256, 256, 0, stream>>>(ei, deg);
    k_scan <<<1, 1024, 0, stream>>>(deg, rowp);
    k_fill <<<(N_EDGES + 255) / 256, 256, 0, stream>>>(ei, rowp, fil, colx);

    // layer 1: h1 stored in d_out
    k_aggregate<<<(N_NODES + 3) / 4, 256, 0, stream>>>(x, rowp, colx, deg, M);
    k_gemm<<<(N_NODES + NPB - 1) / NPB, 128, 0, stream>>>(M, x, W1l, b1l, W1r,
                                                          nullptr, out, 0);
    // layer 2: reads h1 from d_out, writes h1+h2 in place (blocks touch only own rows)
    k_aggregate<<<(N_NODES + 3) / 4, 256, 0, stream>>>(out, rowp, colx, deg, M);
    k_gemm<<<(N_NODES + NPB - 1) / NPB, 128, 0, stream>>>(M, out, W2l, b2l, W2r,
                                                          out, out, 1);
}

// Round 2
// 431.699 us; speedup vs baseline: 1.6961x; 1.6961x over previous
//
#include <hip/hip_runtime.h>

#define N_NODES 50000
#define N_EDGES 800000
#define D 128

typedef __attribute__((ext_vector_type(8))) short bf16x8;
typedef __attribute__((ext_vector_type(4))) float f32x4;

__device__ __forceinline__ float bf2f(unsigned short u) {
    unsigned int x = ((unsigned int)u) << 16;
    return __builtin_bit_cast(float, x);
}
__device__ __forceinline__ unsigned short f2bf(float f) {
    unsigned int u = __builtin_bit_cast(unsigned int, f);
    unsigned int r = (u + 0x7fffu + ((u >> 16) & 1u)) >> 16;   // RNE
    return (unsigned short)r;
}

// ---------------- CSR build ----------------

__global__ __launch_bounds__(256) void k_count(const int* __restrict__ ei,
                                               int* __restrict__ deg) {
    int e = blockIdx.x * 256 + threadIdx.x;
    if (e < N_EDGES) atomicAdd(&deg[ei[N_EDGES + e]], 1);   // dst = ei[1][e]
}

__global__ __launch_bounds__(1024) void k_scan(const int* __restrict__ deg,
                                               int* __restrict__ rowp) {
    const int CH = (N_NODES + 1023) / 1024;   // 49 per thread
    __shared__ int s[1024];
    int t = threadIdx.x;
    int lo = t * CH;
    int hi = lo + CH; if (hi > N_NODES) hi = N_NODES;
    int sum = 0;
    for (int i = lo; i < hi; ++i) sum += deg[i];
    s[t] = sum;
    __syncthreads();
    for (int off = 1; off < 1024; off <<= 1) {
        int u = (t >= off) ? s[t - off] : 0;
        __syncthreads();
        s[t] += u;
        __syncthreads();
    }
    int run = (t > 0) ? s[t - 1] : 0;
    for (int i = lo; i < hi; ++i) { rowp[i] = run; run += deg[i]; }
    if (t == 1023) rowp[N_NODES] = s[1023];
}

__global__ __launch_bounds__(256) void k_fill(const int* __restrict__ ei,
                                              const int* __restrict__ rowp,
                                              int* __restrict__ fil,
                                              int* __restrict__ colx) {
    int e = blockIdx.x * 256 + threadIdx.x;
    if (e < N_EDGES) {
        int dst = ei[N_EDGES + e];
        int p = rowp[dst] + atomicAdd(&fil[dst], 1);
        colx[p] = ei[e];                 // src = ei[0][e]
    }
}

// ---------------- fp32 -> bf16 conversions ----------------

__global__ __launch_bounds__(256) void k_cvt(const float* __restrict__ in,
                                             ushort* __restrict__ out, int n4) {
    int i = blockIdx.x * 256 + threadIdx.x;
    if (i >= n4) return;
    float4 v = ((const float4*)in)[i];
    ushort4 o;
    o.x = f2bf(v.x); o.y = f2bf(v.y); o.z = f2bf(v.z); o.w = f2bf(v.w);
    ((ushort4*)out)[i] = o;
}

__global__ __launch_bounds__(256) void k_cvtw(const float* __restrict__ w0,
                                              const float* __restrict__ w1,
                                              const float* __restrict__ w2,
                                              const float* __restrict__ w3,
                                              ushort* o0, ushort* o1,
                                              ushort* o2, ushort* o3) {
    int b = blockIdx.x >> 4;                        // which W (4096 float4 each)
    int i = (blockIdx.x & 15) * 256 + threadIdx.x;  // float4 index
    const float* in = (b == 0) ? w0 : (b == 1) ? w1 : (b == 2) ? w2 : w3;
    ushort*     out = (b == 0) ? o0 : (b == 1) ? o1 : (b == 2) ? o2 : o3;
    float4 v = ((const float4*)in)[i];
    ushort4 o;
    o.x = f2bf(v.x); o.y = f2bf(v.y); o.z = f2bf(v.z); o.w = f2bf(v.w);
    ((ushort4*)out)[i] = o;
}

// ---------------- mean aggregation (bf16 in/out, fp32 accum) ----------------
// 32 lanes per node, 8B (4 bf16) per lane -> one 256B coalesced row read.

__global__ __launch_bounds__(256) void k_agg(const ushort* __restrict__ Xb,
                                             const int* __restrict__ rowp,
                                             const int* __restrict__ colx,
                                             ushort* __restrict__ Mb) {
    int t = blockIdx.x * 256 + threadIdx.x;
    int node = t >> 5;
    int sl = t & 31;
    if (node >= N_NODES) return;
    int beg = rowp[node], end = rowp[node + 1];
    float a0 = 0.f, a1 = 0.f, a2 = 0.f, a3 = 0.f;
    for (int j = beg; j < end; ++j) {
        int s = colx[j];
        ushort4 v = *(const ushort4*)(Xb + (size_t)s * D + sl * 4);
        a0 += bf2f(v.x); a1 += bf2f(v.y); a2 += bf2f(v.z); a3 += bf2f(v.w);
    }
    float inv = 1.0f / fmaxf((float)(end - beg), 1.0f);
    ushort4 o;
    o.x = f2bf(a0 * inv); o.y = f2bf(a1 * inv);
    o.z = f2bf(a2 * inv); o.w = f2bf(a3 * inv);
    *(ushort4*)(Mb + (size_t)node * D + sl * 4) = o;
}

// ---------------- MFMA GEMM + bias + L2-normalize + act/residual ----------------
// out[i,:] = normalize( [Mb_i | Xb_i] @ [Wl | Wr]^T + b );  64 rows/block, 4 waves.
// A-frag: lane holds A[l&15][(l>>4)*8 + j];  B-frag: lane holds W[l&15 + 16c][k...]
// C/D: row = 4*(l>>4) + i, col = 16c + (l&15)   [guide m89/m91 verified mapping]

__global__ __launch_bounds__(256) void k_gemm(const ushort* __restrict__ Ab_m,
                                              const ushort* __restrict__ Ab_x,
                                              const ushort* __restrict__ Wl,
                                              const ushort* __restrict__ Wr,
                                              const float* __restrict__ bias,
                                              const float* h1,
                                              float* out,
                                              ushort* h1b,
                                              int mode) {
    int lane = threadIdx.x & 63;
    int wid = threadIdx.x >> 6;
    int r = lane & 15, g = lane >> 4;
    int row0 = blockIdx.x * 64 + wid * 16;
    int anode = row0 + r;
    bool avalid = anode < N_NODES;
    const ushort* am = Ab_m + (size_t)anode * D + g * 8;
    const ushort* ax = Ab_x + (size_t)anode * D + g * 8;

    f32x4 acc[8];
    #pragma unroll
    for (int c = 0; c < 8; ++c) acc[c] = (f32x4){0.f, 0.f, 0.f, 0.f};

    #pragma unroll
    for (int s = 0; s < 8; ++s) {
        bf16x8 a = (bf16x8){0, 0, 0, 0, 0, 0, 0, 0};
        if (avalid) a = *(const bf16x8*)((s < 4 ? am : ax) + (s & 3) * 32);
        const ushort* wbase = (s < 4 ? Wl : Wr) + (s & 3) * 32 + g * 8;
        #pragma unroll
        for (int c = 0; c < 8; ++c) {
            bf16x8 b = *(const bf16x8*)(wbase + (size_t)(c * 16 + r) * D);
            acc[c] = __builtin_amdgcn_mfma_f32_16x16x32_bf16(a, b, acc[c], 0, 0, 0);
        }
    }

    // bias before norm
    #pragma unroll
    for (int c = 0; c < 8; ++c) {
        float bv = bias[c * 16 + r];
        #pragma unroll
        for (int i = 0; i < 4; ++i) acc[c][i] += bv;
    }

    // per-row sum of squares: reduce over the 16 lanes sharing g
    float ss[4];
    #pragma unroll
    for (int i = 0; i < 4; ++i) {
        float s = 0.f;
        #pragma unroll
        for (int c = 0; c < 8; ++c) s += acc[c][i] * acc[c][i];
        ss[i] = s;
    }
    #pragma unroll
    for (int m = 1; m < 16; m <<= 1) {
        #pragma unroll
        for (int i = 0; i < 4; ++i) ss[i] += __shfl_xor(ss[i], m, 64);
    }
    float rn[4];
    #pragma unroll
    for (int i = 0; i < 4; ++i) rn[i] = 1.0f / fmaxf(sqrtf(ss[i]), 1e-12f);

    #pragma unroll
    for (int i = 0; i < 4; ++i) {
        int row = row0 + 4 * g + i;
        if (row >= N_NODES) continue;
        #pragma unroll
        for (int c = 0; c < 8; ++c) {
            int col = c * 16 + r;
            float v = acc[c][i] * rn[i];
            if (mode == 0) {
                v = (v > 0.f) ? v : 0.01f * v;          // leaky_relu
                out[(size_t)row * D + col] = v;          // h1 fp32
                h1b[(size_t)row * D + col] = f2bf(v);    // h1 bf16 for layer 2
            } else {
                out[(size_t)row * D + col] = v + h1[(size_t)row * D + col];
            }
        }
    }
}

// ---------------- launch ----------------

extern "C" void kernel_launch(void* const* d_in, const int* in_sizes, int n_in,
                              void* d_out, int out_size, void* d_ws, size_t ws_size,
                              hipStream_t stream) {
    const float* x   = (const float*)d_in[0];
    const int*   ei  = (const int*)d_in[1];   // int64 in ref, JAX x64-off => int32
    const float* W1l = (const float*)d_in[2];
    const float* b1l = (const float*)d_in[3];
    const float* W1r = (const float*)d_in[4];
    const float* W2l = (const float*)d_in[5];
    const float* b2l = (const float*)d_in[6];
    const float* W2r = (const float*)d_in[7];
    float* out = (float*)d_out;
    char*  ws  = (char*)d_ws;

    // workspace layout (bytes), total ~28.2 MB
    int*    deg  = (int*)(ws + 0);              // 200000
    int*    fil  = (int*)(ws + 204800);         // 200000
    int*    rowp = (int*)(ws + 409600);         // 200004
    int*    colx = (int*)(ws + 614400);         // 3.2 MB
    ushort* xb   = (ushort*)(ws + 3814400);     // 12.8 MB  (becomes h1b after layer 1)
    ushort* Mb   = (ushort*)(ws + 16614400);    // 12.8 MB  (mean buffer, both layers)
    ushort* Wb   = (ushort*)(ws + 29414400);    // 128 KB   (4x bf16 weights)
    ushort* W1lb = Wb;
    ushort* W1rb = Wb + 16384;
    ushort* W2lb = Wb + 32768;
    ushort* W2rb = Wb + 49152;

    hipMemsetAsync(ws, 0, 409600, stream);      // deg + fil

    k_cvt <<<6250, 256, 0, stream>>>(x, xb, (N_NODES * D) / 4);
    k_cvtw<<<64, 256, 0, stream>>>(W1l, W1r, W2l, W2r, W1lb, W1rb, W2lb, W2rb);

    k_count<<<(N_EDGES + 255) / 256, 256, 0, stream>>>(ei, deg);
    k_scan <<<1, 1024, 0, stream>>>(deg, rowp);
    k_fill <<<(N_EDGES + 255) / 256, 256, 0, stream>>>(ei, rowp, fil, colx);

    // layer 1: h1 fp32 -> d_out, h1 bf16 -> xb (in place, block-local rows)
    k_agg <<<(N_NODES * 32) / 256 + 1, 256, 0, stream>>>(xb, rowp, colx, Mb);
    k_gemm<<<(N_NODES + 63) / 64, 256, 0, stream>>>(Mb, xb, W1lb, W1rb, b1l,
                                                    nullptr, out, xb, 0);
    // layer 2: reads h1 (bf16 from xb, fp32 from d_out), writes h1+h2 in place
    k_agg <<<(N_NODES * 32) / 256 + 1, 256, 0, stream>>>(xb, rowp, colx, Mb);
    k_gemm<<<(N_NODES + 63) / 64, 256, 0, stream>>>(Mb, xb, W2lb, W2rb, b2l,
                                                    out, out, nullptr, 1);
}

// Round 3
// 315.484 us; speedup vs baseline: 2.3209x; 1.3684x over previous
//
#include <hip/hip_runtime.h>

#define N_NODES 50000
#define N_EDGES 800000
#define D 128

typedef __attribute__((ext_vector_type(8))) short bf16x8;
typedef __attribute__((ext_vector_type(4))) float f32x4;

__device__ __forceinline__ float bf2f(unsigned short u) {
    unsigned int x = ((unsigned int)u) << 16;
    return __builtin_bit_cast(float, x);
}
__device__ __forceinline__ unsigned short f2bf(float f) {
    unsigned int u = __builtin_bit_cast(unsigned int, f);
    unsigned int r = (u + 0x7fffu + ((u >> 16) & 1u)) >> 16;   // RNE
    return (unsigned short)r;
}

// ---------------- CSR build ----------------

__global__ __launch_bounds__(256) void k_count(const int* __restrict__ ei,
                                               int* __restrict__ deg) {
    int e = blockIdx.x * 256 + threadIdx.x;
    if (e < N_EDGES) atomicAdd(&deg[ei[N_EDGES + e]], 1);   // dst = ei[1][e]
}

// hierarchical exclusive scan of deg[50000] -> rowp
__global__ __launch_bounds__(256) void k_scan1(const int* __restrict__ deg,
                                               int* __restrict__ rowp,
                                               int* __restrict__ bsum) {
    __shared__ int s[256];
    int t = threadIdx.x;
    int i = blockIdx.x * 256 + t;
    int v = (i < N_NODES) ? deg[i] : 0;
    s[t] = v;
    __syncthreads();
    for (int off = 1; off < 256; off <<= 1) {
        int u = (t >= off) ? s[t - off] : 0;
        __syncthreads();
        s[t] += u;
        __syncthreads();
    }
    if (i < N_NODES) rowp[i] = s[t] - v;          // exclusive within block
    if (t == 255) bsum[blockIdx.x] = s[255];
}

__global__ __launch_bounds__(256) void k_scan2(int* __restrict__ bsum, int nb) {
    __shared__ int s[256];
    int t = threadIdx.x;
    int v = (t < nb) ? bsum[t] : 0;
    s[t] = v;
    __syncthreads();
    for (int off = 1; off < 256; off <<= 1) {
        int u = (t >= off) ? s[t - off] : 0;
        __syncthreads();
        s[t] += u;
        __syncthreads();
    }
    if (t < nb) bsum[t] = s[t] - v;               // exclusive block prefix
}

__global__ __launch_bounds__(256) void k_scan3(int* __restrict__ rowp,
                                               const int* __restrict__ bsum) {
    int i = blockIdx.x * 256 + threadIdx.x;
    if (i < N_NODES) rowp[i] += bsum[blockIdx.x];
    if (i == 0) rowp[N_NODES] = N_EDGES;          // every edge has a dst
}

__global__ __launch_bounds__(256) void k_fill(const int* __restrict__ ei,
                                              const int* __restrict__ rowp,
                                              int* __restrict__ fil,
                                              int* __restrict__ colx) {
    int e = blockIdx.x * 256 + threadIdx.x;
    if (e < N_EDGES) {
        int dst = ei[N_EDGES + e];
        int p = rowp[dst] + atomicAdd(&fil[dst], 1);
        colx[p] = ei[e];                 // src = ei[0][e]
    }
}

// ---------------- fp32 -> bf16 conversions ----------------

__global__ __launch_bounds__(256) void k_cvt(const float* __restrict__ in,
                                             ushort* __restrict__ out, int n4) {
    int i = blockIdx.x * 256 + threadIdx.x;
    if (i >= n4) return;
    float4 v = ((const float4*)in)[i];
    ushort4 o;
    o.x = f2bf(v.x); o.y = f2bf(v.y); o.z = f2bf(v.z); o.w = f2bf(v.w);
    ((ushort4*)out)[i] = o;
}

__global__ __launch_bounds__(256) void k_cvtw(const float* __restrict__ w0,
                                              const float* __restrict__ w1,
                                              const float* __restrict__ w2,
                                              const float* __restrict__ w3,
                                              ushort* o0, ushort* o1,
                                              ushort* o2, ushort* o3) {
    int b = blockIdx.x >> 4;                        // which W (4096 float4 each)
    int i = (blockIdx.x & 15) * 256 + threadIdx.x;  // float4 index
    const float* in = (b == 0) ? w0 : (b == 1) ? w1 : (b == 2) ? w2 : w3;
    ushort*     out = (b == 0) ? o0 : (b == 1) ? o1 : (b == 2) ? o2 : o3;
    float4 v = ((const float4*)in)[i];
    ushort4 o;
    o.x = f2bf(v.x); o.y = f2bf(v.y); o.z = f2bf(v.z); o.w = f2bf(v.w);
    ((ushort4*)out)[i] = o;
}

// ---------------- mean aggregation (bf16 in/out, fp32 accum) ----------------
// 32 lanes per node: lanes 0-15 take even neighbors, 16-31 odd neighbors,
// 16B (8 bf16) per lane -> each gather iteration covers two 256B rows.
// 2x manual unroll -> 4 independent 16B loads in flight per 32-lane group.

__global__ __launch_bounds__(256) void k_agg(const ushort* __restrict__ Xb,
                                             const int* __restrict__ rowp,
                                             const int* __restrict__ colx,
                                             ushort* __restrict__ Mb) {
    int t = blockIdx.x * 256 + threadIdx.x;
    int node = t >> 5;
    int sl = threadIdx.x & 15;          // 16B slot within row
    int half = (threadIdx.x >> 4) & 1;  // even/odd neighbor stream
    if (node >= N_NODES) return;
    int beg = rowp[node], end = rowp[node + 1];
    float a[8] = {0.f, 0.f, 0.f, 0.f, 0.f, 0.f, 0.f, 0.f};
    int j = beg + half;
    for (; j + 2 < end; j += 4) {
        int s0 = colx[j], s1 = colx[j + 2];
        bf16x8 v0 = *(const bf16x8*)(Xb + (size_t)s0 * D + sl * 8);
        bf16x8 v1 = *(const bf16x8*)(Xb + (size_t)s1 * D + sl * 8);
        #pragma unroll
        for (int i = 0; i < 8; ++i) a[i] += bf2f((unsigned short)v0[i]);
        #pragma unroll
        for (int i = 0; i < 8; ++i) a[i] += bf2f((unsigned short)v1[i]);
    }
    for (; j < end; j += 2) {
        int s0 = colx[j];
        bf16x8 v0 = *(const bf16x8*)(Xb + (size_t)s0 * D + sl * 8);
        #pragma unroll
        for (int i = 0; i < 8; ++i) a[i] += bf2f((unsigned short)v0[i]);
    }
    // combine even/odd partial sums across the 16-lane halves
    #pragma unroll
    for (int i = 0; i < 8; ++i) a[i] += __shfl_xor(a[i], 16, 64);
    if (half == 0) {
        float inv = 1.0f / fmaxf((float)(end - beg), 1.0f);
        bf16x8 o;
        #pragma unroll
        for (int i = 0; i < 8; ++i) o[i] = (short)f2bf(a[i] * inv);
        *(bf16x8*)(Mb + (size_t)node * D + sl * 8) = o;
    }
}

// ---------------- MFMA GEMM + bias + L2-normalize + act/residual ----------------
// out[i,:] = normalize( [Mb_i | Xb_i] @ [Wl | Wr]^T + b );  64 rows/block, 4 waves.
// A-frag: lane holds A[l&15][(l>>4)*8 + j];  B-frag: lane holds W[l&15 + 16c][k...]
// C/D: row = 4*(l>>4) + i, col = 16c + (l&15)   [guide m89/m91 verified mapping]

__global__ __launch_bounds__(256) void k_gemm(const ushort* __restrict__ Ab_m,
                                              const ushort* __restrict__ Ab_x,
                                              const ushort* __restrict__ Wl,
                                              const ushort* __restrict__ Wr,
                                              const float* __restrict__ bias,
                                              const float* h1,
                                              float* out,
                                              ushort* h1b,
                                              int mode) {
    int lane = threadIdx.x & 63;
    int wid = threadIdx.x >> 6;
    int r = lane & 15, g = lane >> 4;
    int row0 = blockIdx.x * 64 + wid * 16;
    int anode = row0 + r;
    bool avalid = anode < N_NODES;
    const ushort* am = Ab_m + (size_t)anode * D + g * 8;
    const ushort* ax = Ab_x + (size_t)anode * D + g * 8;

    f32x4 acc[8];
    #pragma unroll
    for (int c = 0; c < 8; ++c) acc[c] = (f32x4){0.f, 0.f, 0.f, 0.f};

    #pragma unroll
    for (int s = 0; s < 8; ++s) {
        bf16x8 a = (bf16x8){0, 0, 0, 0, 0, 0, 0, 0};
        if (avalid) a = *(const bf16x8*)((s < 4 ? am : ax) + (s & 3) * 32);
        const ushort* wbase = (s < 4 ? Wl : Wr) + (s & 3) * 32 + g * 8;
        #pragma unroll
        for (int c = 0; c < 8; ++c) {
            bf16x8 b = *(const bf16x8*)(wbase + (size_t)(c * 16 + r) * D);
            acc[c] = __builtin_amdgcn_mfma_f32_16x16x32_bf16(a, b, acc[c], 0, 0, 0);
        }
    }

    // bias before norm
    #pragma unroll
    for (int c = 0; c < 8; ++c) {
        float bv = bias[c * 16 + r];
        #pragma unroll
        for (int i = 0; i < 4; ++i) acc[c][i] += bv;
    }

    // per-row sum of squares: reduce over the 16 lanes sharing g
    float ss[4];
    #pragma unroll
    for (int i = 0; i < 4; ++i) {
        float s = 0.f;
        #pragma unroll
        for (int c = 0; c < 8; ++c) s += acc[c][i] * acc[c][i];
        ss[i] = s;
    }
    #pragma unroll
    for (int m = 1; m < 16; m <<= 1) {
        #pragma unroll
        for (int i = 0; i < 4; ++i) ss[i] += __shfl_xor(ss[i], m, 64);
    }
    float rn[4];
    #pragma unroll
    for (int i = 0; i < 4; ++i) rn[i] = 1.0f / fmaxf(sqrtf(ss[i]), 1e-12f);

    #pragma unroll
    for (int i = 0; i < 4; ++i) {
        int row = row0 + 4 * g + i;
        if (row >= N_NODES) continue;
        #pragma unroll
        for (int c = 0; c < 8; ++c) {
            int col = c * 16 + r;
            float v = acc[c][i] * rn[i];
            if (mode == 0) {
                v = (v > 0.f) ? v : 0.01f * v;          // leaky_relu
                out[(size_t)row * D + col] = v;          // h1 fp32
                h1b[(size_t)row * D + col] = f2bf(v);    // h1 bf16 for layer 2
            } else {
                out[(size_t)row * D + col] = v + h1[(size_t)row * D + col];
            }
        }
    }
}

// ---------------- launch ----------------

extern "C" void kernel_launch(void* const* d_in, const int* in_sizes, int n_in,
                              void* d_out, int out_size, void* d_ws, size_t ws_size,
                              hipStream_t stream) {
    const float* x   = (const float*)d_in[0];
    const int*   ei  = (const int*)d_in[1];   // int64 in ref, JAX x64-off => int32
    const float* W1l = (const float*)d_in[2];
    const float* b1l = (const float*)d_in[3];
    const float* W1r = (const float*)d_in[4];
    const float* W2l = (const float*)d_in[5];
    const float* b2l = (const float*)d_in[6];
    const float* W2r = (const float*)d_in[7];
    float* out = (float*)d_out;
    char*  ws  = (char*)d_ws;

    // workspace layout (bytes), total ~28.2 MB (+ bsum tail)
    int*    deg  = (int*)(ws + 0);              // 200000
    int*    fil  = (int*)(ws + 204800);         // 200000
    int*    rowp = (int*)(ws + 409600);         // 200004
    int*    colx = (int*)(ws + 614400);         // 3.2 MB
    ushort* xb   = (ushort*)(ws + 3814400);     // 12.8 MB  (becomes h1b after layer 1)
    ushort* Mb   = (ushort*)(ws + 16614400);    // 12.8 MB  (mean buffer, both layers)
    ushort* Wb   = (ushort*)(ws + 29414400);    // 128 KB   (4x bf16 weights)
    ushort* W1lb = Wb;
    ushort* W1rb = Wb + 16384;
    ushort* W2lb = Wb + 32768;
    ushort* W2rb = Wb + 49152;
    int*    bsum = (int*)(ws + 29545472);       // 784 B (196 block sums)

    hipMemsetAsync(ws, 0, 409600, stream);      // deg + fil

    k_cvt <<<6250, 256, 0, stream>>>(x, xb, (N_NODES * D) / 4);
    k_cvtw<<<64, 256, 0, stream>>>(W1l, W1r, W2l, W2r, W1lb, W1rb, W2lb, W2rb);

    const int NB = (N_NODES + 255) / 256;       // 196
    k_count<<<(N_EDGES + 255) / 256, 256, 0, stream>>>(ei, deg);
    k_scan1<<<NB, 256, 0, stream>>>(deg, rowp, bsum);
    k_scan2<<<1, 256, 0, stream>>>(bsum, NB);
    k_scan3<<<NB, 256, 0, stream>>>(rowp, bsum);
    k_fill <<<(N_EDGES + 255) / 256, 256, 0, stream>>>(ei, rowp, fil, colx);

    // layer 1: h1 fp32 -> d_out, h1 bf16 -> xb (in place, block-local rows)
    k_agg <<<(N_NODES * 32 + 255) / 256, 256, 0, stream>>>(xb, rowp, colx, Mb);
    k_gemm<<<(N_NODES + 63) / 64, 256, 0, stream>>>(Mb, xb, W1lb, W1rb, b1l,
                                                    nullptr, out, xb, 0);
    // layer 2: reads h1 (bf16 from xb, fp32 from d_out), writes h1+h2 in place
    k_agg <<<(N_NODES * 32 + 255) / 256, 256, 0, stream>>>(xb, rowp, colx, Mb);
    k_gemm<<<(N_NODES + 63) / 64, 256, 0, stream>>>(Mb, xb, W2lb, W2rb, b2l,
                                                    out, out, nullptr, 1);
}

// Round 6
// 271.523 us; speedup vs baseline: 2.6967x; 1.1619x over previous
//
#include <hip/hip_runtime.h>

#define N_NODES 50000
#define N_EDGES 800000
#define D 128

typedef __attribute__((ext_vector_type(8))) short bf16x8;
typedef __attribute__((ext_vector_type(4))) float f32x4;

__device__ __forceinline__ float bf2f(unsigned short u) {
    unsigned int x = ((unsigned int)u) << 16;
    return __builtin_bit_cast(float, x);
}
__device__ __forceinline__ unsigned short f2bf(float f) {
    unsigned int u = __builtin_bit_cast(unsigned int, f);
    unsigned int r = (u + 0x7fffu + ((u >> 16) & 1u)) >> 16;   // RNE
    return (unsigned short)r;
}

// ---------------- CSR build ----------------

__global__ __launch_bounds__(256) void k_count(const int* __restrict__ ei,
                                               int* __restrict__ deg) {
    int e = blockIdx.x * 256 + threadIdx.x;
    if (e < N_EDGES) atomicAdd(&deg[ei[N_EDGES + e]], 1);   // dst = ei[1][e]
}

// hierarchical exclusive scan of deg[50000] -> rowp
__global__ __launch_bounds__(256) void k_scan1(const int* __restrict__ deg,
                                               int* __restrict__ rowp,
                                               int* __restrict__ bsum) {
    __shared__ int s[256];
    int t = threadIdx.x;
    int i = blockIdx.x * 256 + t;
    int v = (i < N_NODES) ? deg[i] : 0;
    s[t] = v;
    __syncthreads();
    for (int off = 1; off < 256; off <<= 1) {
        int u = (t >= off) ? s[t - off] : 0;
        __syncthreads();
        s[t] += u;
        __syncthreads();
    }
    if (i < N_NODES) rowp[i] = s[t] - v;          // exclusive within block
    if (t == 255) bsum[blockIdx.x] = s[255];
}

__global__ __launch_bounds__(256) void k_scan2(int* __restrict__ bsum, int nb) {
    __shared__ int s[256];
    int t = threadIdx.x;
    int v = (t < nb) ? bsum[t] : 0;
    s[t] = v;
    __syncthreads();
    for (int off = 1; off < 256; off <<= 1) {
        int u = (t >= off) ? s[t - off] : 0;
        __syncthreads();
        s[t] += u;
        __syncthreads();
    }
    if (t < nb) bsum[t] = s[t] - v;               // exclusive block prefix
}

__global__ __launch_bounds__(256) void k_scan3(int* __restrict__ rowp,
                                               const int* __restrict__ bsum) {
    int i = blockIdx.x * 256 + threadIdx.x;
    if (i < N_NODES) rowp[i] += bsum[blockIdx.x];
    if (i == 0) rowp[N_NODES] = N_EDGES;          // every edge has a dst
}

__global__ __launch_bounds__(256) void k_fill(const int* __restrict__ ei,
                                              const int* __restrict__ rowp,
                                              int* __restrict__ fil,
                                              int* __restrict__ colx) {
    int e = blockIdx.x * 256 + threadIdx.x;
    if (e < N_EDGES) {
        int dst = ei[N_EDGES + e];
        int p = rowp[dst] + atomicAdd(&fil[dst], 1);
        colx[p] = ei[e];                 // src = ei[0][e]
    }
}

// ---------------- fp32 -> bf16 conversions ----------------

__global__ __launch_bounds__(256) void k_cvt(const float* __restrict__ in,
                                             ushort* __restrict__ out, int n4) {
    int i = blockIdx.x * 256 + threadIdx.x;
    if (i >= n4) return;
    float4 v = ((const float4*)in)[i];
    ushort4 o;
    o.x = f2bf(v.x); o.y = f2bf(v.y); o.z = f2bf(v.z); o.w = f2bf(v.w);
    ((ushort4*)out)[i] = o;
}

__global__ __launch_bounds__(256) void k_cvtw(const float* __restrict__ w0,
                                              const float* __restrict__ w1,
                                              const float* __restrict__ w2,
                                              const float* __restrict__ w3,
                                              ushort* o0, ushort* o1,
                                              ushort* o2, ushort* o3) {
    int b = blockIdx.x >> 4;                        // which W (4096 float4 each)
    int i = (blockIdx.x & 15) * 256 + threadIdx.x;  // float4 index
    const float* in = (b == 0) ? w0 : (b == 1) ? w1 : (b == 2) ? w2 : w3;
    ushort*     out = (b == 0) ? o0 : (b == 1) ? o1 : (b == 2) ? o2 : o3;
    float4 v = ((const float4*)in)[i];
    ushort4 o;
    o.x = f2bf(v.x); o.y = f2bf(v.y); o.z = f2bf(v.z); o.w = f2bf(v.w);
    ((ushort4*)out)[i] = o;
}

// ---------------- mean aggregation (bf16 in/out, fp32 accum) ----------------
// 32 lanes per node: lanes 0-15 even neighbors, 16-31 odd, 16B/lane.

__global__ __launch_bounds__(256) void k_agg(const ushort* __restrict__ Xb,
                                             const int* __restrict__ rowp,
                                             const int* __restrict__ colx,
                                             ushort* __restrict__ Mb) {
    int t = blockIdx.x * 256 + threadIdx.x;
    int node = t >> 5;
    int sl = threadIdx.x & 15;          // 16B slot within row
    int half = (threadIdx.x >> 4) & 1;  // even/odd neighbor stream
    if (node >= N_NODES) return;
    int beg = rowp[node], end = rowp[node + 1];
    float a[8] = {0.f, 0.f, 0.f, 0.f, 0.f, 0.f, 0.f, 0.f};
    int j = beg + half;
    for (; j + 2 < end; j += 4) {
        int s0 = colx[j], s1 = colx[j + 2];
        bf16x8 v0 = *(const bf16x8*)(Xb + (size_t)s0 * D + sl * 8);
        bf16x8 v1 = *(const bf16x8*)(Xb + (size_t)s1 * D + sl * 8);
        #pragma unroll
        for (int i = 0; i < 8; ++i) a[i] += bf2f((unsigned short)v0[i]);
        #pragma unroll
        for (int i = 0; i < 8; ++i) a[i] += bf2f((unsigned short)v1[i]);
    }
    for (; j < end; j += 2) {
        int s0 = colx[j];
        bf16x8 v0 = *(const bf16x8*)(Xb + (size_t)s0 * D + sl * 8);
        #pragma unroll
        for (int i = 0; i < 8; ++i) a[i] += bf2f((unsigned short)v0[i]);
    }
    #pragma unroll
    for (int i = 0; i < 8; ++i) a[i] += __shfl_xor(a[i], 16, 64);
    if (half == 0) {
        float inv = 1.0f / fmaxf((float)(end - beg), 1.0f);
        bf16x8 o;
        #pragma unroll
        for (int i = 0; i < 8; ++i) o[i] = (short)f2bf(a[i] * inv);
        *(bf16x8*)(Mb + (size_t)node * D + sl * 8) = o;
    }
}

// ---------------- MFMA GEMM: W staged in swizzled LDS ----------------
// Wcat = [Wl | Wr] viewed as [128 outcols][256 k'] bf16 (row = 512B).
// LDS swizzle: byte ^= (row&7)<<4  -> 16 lanes at fixed (c,s,g) hit 8 distinct
// 16B slots = all 32 banks, 2-way alias (free, m136).
// A-frag: lane holds A[l&15][(l>>4)*8+j]; C/D: row=4*(l>>4)+i, col=16c+(l&15).
// mode 0: h1 = leaky(norm(...)) -> h1b (bf16 only).
// mode 1: out = norm(...) + bf2f(h1b)  (fp32).

__global__ __launch_bounds__(256) void k_gemm(const ushort* __restrict__ Ab_m,
                                              const ushort* __restrict__ Ab_x,
                                              const ushort* __restrict__ Wl,
                                              const ushort* __restrict__ Wr,
                                              const float* __restrict__ bias,
                                              const ushort* __restrict__ h1b_in,
                                              float* __restrict__ out,
                                              ushort* __restrict__ h1b_out,
                                              int mode) {
    __shared__ ushort Wlds[32768];     // 64 KB
    int tid = threadIdx.x;

    // stage 4096 x 16B chunks, swizzled; coalesced global reads
    #pragma unroll
    for (int jj = 0; jj < 16; ++jj) {
        int n = jj * 256 + tid;
        int row = n >> 5, c16 = n & 31;
        const ushort* src = (c16 < 16) ? (Wl + row * 128 + c16 * 8)
                                       : (Wr + row * 128 + (c16 - 16) * 8);
        bf16x8 v = *(const bf16x8*)src;
        int slot = row * 32 + (c16 ^ (row & 7));
        *(bf16x8*)(Wlds + slot * 8) = v;
    }
    __syncthreads();

    int lane = tid & 63;
    int wid = tid >> 6;
    int r = lane & 15, g = lane >> 4;
    int row0 = blockIdx.x * 64 + wid * 16;
    int anode = row0 + r;
    bool avalid = anode < N_NODES;
    const ushort* am = Ab_m + (size_t)anode * D + g * 8;
    const ushort* ax = Ab_x + (size_t)anode * D + g * 8;

    f32x4 acc[8];
    #pragma unroll
    for (int c = 0; c < 8; ++c) acc[c] = (f32x4){0.f, 0.f, 0.f, 0.f};

    #pragma unroll
    for (int s = 0; s < 8; ++s) {
        bf16x8 a = (bf16x8){0, 0, 0, 0, 0, 0, 0, 0};
        if (avalid) a = *(const bf16x8*)((s < 4 ? am : ax) + (s & 3) * 32);
        #pragma unroll
        for (int c = 0; c < 8; ++c) {
            int wrow = c * 16 + r;
            int byte = (wrow * 512 + s * 64 + g * 16) ^ ((wrow & 7) << 4);
            bf16x8 b = *(const bf16x8*)((const char*)Wlds + byte);
            acc[c] = __builtin_amdgcn_mfma_f32_16x16x32_bf16(a, b, acc[c], 0, 0, 0);
        }
    }

    // bias before norm
    #pragma unroll
    for (int c = 0; c < 8; ++c) {
        float bv = bias[c * 16 + r];
        #pragma unroll
        for (int i = 0; i < 4; ++i) acc[c][i] += bv;
    }

    // per-row sum of squares over the 16 lanes sharing g
    float ss[4];
    #pragma unroll
    for (int i = 0; i < 4; ++i) {
        float s = 0.f;
        #pragma unroll
        for (int c = 0; c < 8; ++c) s += acc[c][i] * acc[c][i];
        ss[i] = s;
    }
    #pragma unroll
    for (int m = 1; m < 16; m <<= 1) {
        #pragma unroll
        for (int i = 0; i < 4; ++i) ss[i] += __shfl_xor(ss[i], m, 64);
    }
    float rn[4];
    #pragma unroll
    for (int i = 0; i < 4; ++i) rn[i] = 1.0f / fmaxf(sqrtf(ss[i]), 1e-12f);

    #pragma unroll
    for (int i = 0; i < 4; ++i) {
        int row = row0 + 4 * g + i;
        if (row >= N_NODES) continue;
        #pragma unroll
        for (int c = 0; c < 8; ++c) {
            int col = c * 16 + r;
            float v = acc[c][i] * rn[i];
            if (mode == 0) {
                v = (v > 0.f) ? v : 0.01f * v;               // leaky_relu
                h1b_out[(size_t)row * D + col] = f2bf(v);     // h1 kept bf16 only
            } else {
                v += bf2f(h1b_in[(size_t)row * D + col]);     // h1 + h2
                out[(size_t)row * D + col] = v;
            }
        }
    }
}

// ---------------- launch ----------------

extern "C" void kernel_launch(void* const* d_in, const int* in_sizes, int n_in,
                              void* d_out, int out_size, void* d_ws, size_t ws_size,
                              hipStream_t stream) {
    const float* x   = (const float*)d_in[0];
    const int*   ei  = (const int*)d_in[1];   // int64 in ref, JAX x64-off => int32
    const float* W1l = (const float*)d_in[2];
    const float* b1l = (const float*)d_in[3];
    const float* W1r = (const float*)d_in[4];
    const float* W2l = (const float*)d_in[5];
    const float* b2l = (const float*)d_in[6];
    const float* W2r = (const float*)d_in[7];
    float* out = (float*)d_out;
    char*  ws  = (char*)d_ws;

    // workspace layout (bytes), total ~28.2 MB (+ bsum tail)
    int*    deg  = (int*)(ws + 0);              // 200000
    int*    fil  = (int*)(ws + 204800);         // 200000
    int*    rowp = (int*)(ws + 409600);         // 200004
    int*    colx = (int*)(ws + 614400);         // 3.2 MB
    ushort* xb   = (ushort*)(ws + 3814400);     // 12.8 MB  (becomes h1b after layer 1)
    ushort* Mb   = (ushort*)(ws + 16614400);    // 12.8 MB  (mean buffer, both layers)
    ushort* Wb   = (ushort*)(ws + 29414400);    // 128 KB   (4x bf16 weights)
    ushort* W1lb = Wb;
    ushort* W1rb = Wb + 16384;
    ushort* W2lb = Wb + 32768;
    ushort* W2rb = Wb + 49152;
    int*    bsum = (int*)(ws + 29545472);       // 784 B (196 block sums)

    hipMemsetAsync(ws, 0, 409600, stream);      // deg + fil

    k_cvt <<<6250, 256, 0, stream>>>(x, xb, (N_NODES * D) / 4);
    k_cvtw<<<64, 256, 0, stream>>>(W1l, W1r, W2l, W2r, W1lb, W1rb, W2lb, W2rb);

    const int NB = (N_NODES + 255) / 256;       // 196
    k_count<<<(N_EDGES + 255) / 256, 256, 0, stream>>>(ei, deg);
    k_scan1<<<NB, 256, 0, stream>>>(deg, rowp, bsum);
    k_scan2<<<1, 256, 0, stream>>>(bsum, NB);
    k_scan3<<<NB, 256, 0, stream>>>(rowp, bsum);
    k_fill <<<(N_EDGES + 255) / 256, 256, 0, stream>>>(ei, rowp, fil, colx);

    // layer 1: h1 bf16 -> xb (in place, block-local rows)
    k_agg <<<(N_NODES * 32 + 255) / 256, 256, 0, stream>>>(xb, rowp, colx, Mb);
    k_gemm<<<(N_NODES + 63) / 64, 256, 0, stream>>>(Mb, xb, W1lb, W1rb, b1l,
                                                    nullptr, out, xb, 0);
    // layer 2: out = bf2f(h1b) + h2  (reads h1b from xb)
    k_agg <<<(N_NODES * 32 + 255) / 256, 256, 0, stream>>>(xb, rowp, colx, Mb);
    k_gemm<<<(N_NODES + 63) / 64, 256, 0, stream>>>(Mb, xb, W2lb, W2rb, b2l,
                                                    xb, out, nullptr, 1);
}